// Round 1
// baseline (250.162 us; speedup 1.0000x reference)
//
#include <hip/hip_runtime.h>
#include <stdint.h>

#define N_NODES 30000
#define NC 256

typedef _Float16 f16x8 __attribute__((ext_vector_type(8)));
typedef _Float16 f16x4 __attribute__((ext_vector_type(4)));
typedef _Float16 f16x2 __attribute__((ext_vector_type(2)));
typedef float f32x4 __attribute__((ext_vector_type(4)));

// ---- convert x (with clip +-10) to f16 ----
__global__ void k_conv_x(const float* __restrict__ x, _Float16* __restrict__ xb) {
    int i = (blockIdx.x * 256 + threadIdx.x) * 4;   // total 7,680,000 -> 7500 blocks
    float4 v = *reinterpret_cast<const float4*>(x + i);
    f16x4 o;
    o[0] = (_Float16)fminf(fmaxf(v.x, -10.f), 10.f);
    o[1] = (_Float16)fminf(fmaxf(v.y, -10.f), 10.f);
    o[2] = (_Float16)fminf(fmaxf(v.z, -10.f), 10.f);
    o[3] = (_Float16)fminf(fmaxf(v.w, -10.f), 10.f);
    *reinterpret_cast<f16x4*>(xb + i) = o;
}

// ---- convert W = [w_real; w_imag] ([512][256]) to f16 ----
__global__ void k_conv_w(const float* __restrict__ wr, const float* __restrict__ wi,
                         _Float16* __restrict__ Wb) {
    int i = (blockIdx.x * 256 + threadIdx.x) * 4;   // total 131,072 -> 128 blocks
    const float* src = (i < NC * NC) ? (wr + i) : (wi + (i - NC * NC));
    float4 v = *reinterpret_cast<const float4*>(src);
    f16x4 o;
    o[0] = (_Float16)v.x; o[1] = (_Float16)v.y;
    o[2] = (_Float16)v.z; o[3] = (_Float16)v.w;
    *reinterpret_cast<f16x4*>(Wb + i) = o;
}

// ---- GEMM: H[i][j] = sum_k A[i,k]*W[j,k] + bias[j], f16 MFMA 16x16x32 ----
// 128x128 block tile, 4 waves each computing 64x64 (4x4 mfma tiles).
// Output stored interleaved: channel c -> (re,im) f16 pair at H[i*512 + 2c(+1)]
__global__ __launch_bounds__(256) void k_gemm(
    const _Float16* __restrict__ A, const _Float16* __restrict__ B,
    const float* __restrict__ br, const float* __restrict__ bi,
    _Float16* __restrict__ H)
{
    int bid = blockIdx.x;
    int bm = bid >> 2, bn = bid & 3;          // 235 x 4 blocks
    int tid = threadIdx.x;
    int lane = tid & 63, wave = tid >> 6;
    int quad = lane >> 4, l16 = lane & 15;
    int wm = wave >> 1, wn = wave & 1;
    int row0 = bm * 128 + wm * 64;
    int col0 = bn * 128 + wn * 64;

    const _Float16* ap[4];
    const _Float16* bp[4];
#pragma unroll
    for (int mi = 0; mi < 4; mi++) {
        int r = row0 + mi * 16 + l16;
        if (r >= N_NODES) r = N_NODES - 1;    // clamp: garbage rows never stored
        ap[mi] = A + r * NC + quad * 8;
    }
#pragma unroll
    for (int ni = 0; ni < 4; ni++)
        bp[ni] = B + (col0 + ni * 16 + l16) * NC + quad * 8;

    f32x4 acc[4][4] = {};
    for (int k = 0; k < NC; k += 32) {
        f16x8 af[4], bfr[4];
#pragma unroll
        for (int mi = 0; mi < 4; mi++) af[mi] = *reinterpret_cast<const f16x8*>(ap[mi] + k);
#pragma unroll
        for (int ni = 0; ni < 4; ni++) bfr[ni] = *reinterpret_cast<const f16x8*>(bp[ni] + k);
#pragma unroll
        for (int mi = 0; mi < 4; mi++)
#pragma unroll
            for (int ni = 0; ni < 4; ni++)
                acc[mi][ni] = __builtin_amdgcn_mfma_f32_16x16x32_f16(
                    af[mi], bfr[ni], acc[mi][ni], 0, 0, 0);
    }
    // epilogue: D row = quad*4 + r, col = l16 (within 16x16 tile)
#pragma unroll
    for (int ni = 0; ni < 4; ni++) {
        int col = col0 + ni * 16 + l16;
        float bias = (col < NC) ? br[col] : bi[col - NC];
        int cc = (col < NC) ? (col * 2) : ((col - NC) * 2 + 1);
#pragma unroll
        for (int mi = 0; mi < 4; mi++) {
            int rowb = row0 + mi * 16 + quad * 4;
#pragma unroll
            for (int r = 0; r < 4; r++) {
                int row = rowb + r;
                if (row < N_NODES) H[row * 512 + cc] = (_Float16)(acc[mi][ni][r] + bias);
            }
        }
    }
}

// ---- evolve: out = x + esc*(h[i] - i*sum_s g_s h[n_s]); accumulate mag stats ----
#define NPB 128
__global__ __launch_bounds__(256) void k_evolve(
    const float* __restrict__ x, const int* __restrict__ sub_nodes,
    const float* __restrict__ sub_mask, const float* __restrict__ subH,
    const _Float16* __restrict__ h, const float* __restrict__ escp,
    float* __restrict__ outz, float* __restrict__ ssum, float* __restrict__ ssumsq)
{
    __shared__ int   s_nodes[NPB][4];
    __shared__ float s_g[NPB][4];
    __shared__ float s_m0[NPB];
    int tid = threadIdx.x;
    int base = blockIdx.x * NPB;
    if (tid < NPB) {
        int node = base + tid;
        if (node < N_NODES) {
            float fr = 0.f;
#pragma unroll
            for (int t = 0; t < 16; t++) { float v = subH[node * 16 + t]; fr += v * v; }
            // A = -i * H * 1e-4/||H||_F  (eigen- and norm-clamps provably always fire
            // and their scalar factors cancel; Taylor >=2nd order terms are <=5e-9)
            float coef = 1e-4f * rsqrtf(fr);
#pragma unroll
            for (int s = 0; s < 4; s++) {
                s_g[tid][s]     = coef * subH[node * 16 + s] * sub_mask[node * 4 + s];
                s_nodes[tid][s] = sub_nodes[node * 4 + s];
            }
            s_m0[tid] = sub_mask[node * 4];
        }
    }
    __syncthreads();
    float esc = *escp;
    float lsum = 0.f, lsq = 0.f;
    int nmax = N_NODES - base; if (nmax > NPB) nmax = NPB;
    for (int j = 0; j < nmax; j++) {
        int node = base + j;
        float evr = 0.f, evi = 0.f;
#pragma unroll
        for (int s = 0; s < 4; s++) {
            int ns = s_nodes[j][s];
            float g = s_g[j][s];
            f16x2 v = *reinterpret_cast<const f16x2*>(h + ns * 512 + tid * 2);
            float hr = (float)v[0], hi = (float)v[1];
            evr += g * hi;           // -i*g*(hr + i*hi) = g*hi - i*g*hr
            evi -= g * hr;
            if (s == 0) { float m0 = s_m0[j]; evr += m0 * hr; evi += m0 * hi; }
        }
        float xr = x[node * NC + tid];
        float outr = fmaf(esc, evr, xr);
        float outi = esc * evi;
        outz[node * 512 + tid] = outr;
        outz[node * 512 + 256 + tid] = outi;
        float mag = sqrtf(fmaf(outr, outr, fmaf(outi, outi, 1e-5f)));
        mag = fminf(fmaxf(mag, 1e-5f), 1000.f);
        lsum += mag;
        lsq = fmaf(mag, mag, lsq);
    }
    atomicAdd(&ssum[tid], lsum);     // tid == channel; 235 adds per address
    atomicAdd(&ssumsq[tid], lsq);
}

// ---- layernorm over batch stats + phase + leaky crelu, in place on d_out ----
__global__ __launch_bounds__(256) void k_norm(
    float* __restrict__ outz,
    const float* __restrict__ ssum, const float* __restrict__ ssumsq,
    const float* __restrict__ lnw, const float* __restrict__ lnb)
{
    int idx = blockIdx.x * 256 + threadIdx.x;   // 30000 blocks
    int i = idx >> 8, c = idx & 255;
    if (i >= N_NODES) return;
    const float invN = 1.0f / (float)N_NODES;
    float mean = ssum[c] * invN;
    float var = ssumsq[c] * invN - mean * mean;
    var = fmaxf(var, 0.f);
    float denom = sqrtf(var + 1e-5f) + 1e-5f;
    float re = outz[i * 512 + c];
    float im = outz[i * 512 + 256 + c];
    float mag = sqrtf(fmaf(re, re, fmaf(im, im, 1e-5f)));
    mag = fminf(fmaxf(mag, 1e-5f), 1000.f);
    float nm = (mag - mean) / denom;
    float sm = fmaf(nm, fabsf(lnw[c]), lnb[c]);
    sm = fminf(fmaxf(sm, 1e-5f), 10.0f);
    float px = fminf(fmaxf(re, -1e6f), 1e6f) + 1e-10f;
    float py = fminf(fmaxf(im, -1e6f), 1e6f);
    float r2 = fmaf(px, px, py * py);
    float cs, sn;
    if (r2 > 0.f) { float inv = rsqrtf(r2); cs = px * inv; sn = py * inv; }
    else { cs = 1.f; sn = 0.f; }
    float zr = sm * cs, zi = sm * sn;
    zr = fminf(fmaxf(zr, -5.f), 5.f);
    zi = fminf(fmaxf(zi, -5.f), 5.f);
    zr = zr > 0.f ? zr : 0.01f * zr;
    zi = zi > 0.f ? zi : 0.01f * zi;
    outz[i * 512 + c] = zr;
    outz[i * 512 + 256 + c] = zi;
}

extern "C" void kernel_launch(void* const* d_in, const int* in_sizes, int n_in,
                              void* d_out, int out_size, void* d_ws, size_t ws_size,
                              hipStream_t stream) {
    const float* x        = (const float*)d_in[0];
    // d_in[1] edge_index: unused (sub_nodes/sub_mask/sub_H are precomputed)
    const int*   sub_nodes = (const int*)d_in[2];
    const float* sub_mask  = (const float*)d_in[3];
    const float* subH      = (const float*)d_in[4];
    const float* wr  = (const float*)d_in[5];
    const float* wi  = (const float*)d_in[6];
    const float* br  = (const float*)d_in[7];
    const float* bi  = (const float*)d_in[8];
    const float* lnw = (const float*)d_in[9];
    const float* lnb = (const float*)d_in[10];
    const float* esc = (const float*)d_in[11];
    float* out = (float*)d_out;

    char* ws = (char*)d_ws;
    const size_t XB_OFF  = 0;                         // 30000*256*2  = 15,360,000
    const size_t WB_OFF  = 15360000;                  // 512*256*2    =    262,144
    const size_t H_OFF   = 15622144;                  // 30000*512*2  = 30,720,000
    const size_t SUM_OFF = 46342144;                  // 256*4 + 256*4
    _Float16* xb = (_Float16*)(ws + XB_OFF);
    _Float16* Wb = (_Float16*)(ws + WB_OFF);
    _Float16* h  = (_Float16*)(ws + H_OFF);
    float* ssum   = (float*)(ws + SUM_OFF);
    float* ssumsq = (float*)(ws + SUM_OFF + 1024);

    hipMemsetAsync(ssum, 0, 2048, stream);
    hipLaunchKernelGGL(k_conv_x, dim3(7500), dim3(256), 0, stream, x, xb);
    hipLaunchKernelGGL(k_conv_w, dim3(128), dim3(256), 0, stream, wr, wi, Wb);
    hipLaunchKernelGGL(k_gemm, dim3(235 * 4), dim3(256), 0, stream, xb, Wb, br, bi, h);
    hipLaunchKernelGGL(k_evolve, dim3(235), dim3(256), 0, stream,
                       x, sub_nodes, sub_mask, subH, h, esc, out, ssum, ssumsq);
    hipLaunchKernelGGL(k_norm, dim3(30000), dim3(256), 0, stream,
                       out, ssum, ssumsq, lnw, lnb);
}

// Round 2
// 224.943 us; speedup vs baseline: 1.1121x; 1.1121x over previous
//
#include <hip/hip_runtime.h>
#include <stdint.h>

#define N_NODES 30000
#define NC 256

typedef _Float16 f16x8 __attribute__((ext_vector_type(8)));
typedef _Float16 f16x4 __attribute__((ext_vector_type(4)));
typedef _Float16 f16x2 __attribute__((ext_vector_type(2)));
typedef float f32x4 __attribute__((ext_vector_type(4)));

// ---- convert x (with clip +-10) to f16 ----
__global__ void k_conv_x(const float* __restrict__ x, _Float16* __restrict__ xb) {
    int i = (blockIdx.x * 256 + threadIdx.x) * 4;   // total 7,680,000 -> 7500 blocks
    float4 v = *reinterpret_cast<const float4*>(x + i);
    f16x4 o;
    o[0] = (_Float16)fminf(fmaxf(v.x, -10.f), 10.f);
    o[1] = (_Float16)fminf(fmaxf(v.y, -10.f), 10.f);
    o[2] = (_Float16)fminf(fmaxf(v.z, -10.f), 10.f);
    o[3] = (_Float16)fminf(fmaxf(v.w, -10.f), 10.f);
    *reinterpret_cast<f16x4*>(xb + i) = o;
}

// ---- convert W = [w_real; w_imag] ([512][256]) to f16 ----
__global__ void k_conv_w(const float* __restrict__ wr, const float* __restrict__ wi,
                         _Float16* __restrict__ Wb) {
    int i = (blockIdx.x * 256 + threadIdx.x) * 4;   // total 131,072 -> 128 blocks
    const float* src = (i < NC * NC) ? (wr + i) : (wi + (i - NC * NC));
    float4 v = *reinterpret_cast<const float4*>(src);
    f16x4 o;
    o[0] = (_Float16)v.x; o[1] = (_Float16)v.y;
    o[2] = (_Float16)v.z; o[3] = (_Float16)v.w;
    *reinterpret_cast<f16x4*>(Wb + i) = o;
}

// ---- GEMM: H[i][j] = sum_k A[i,k]*W[j,k] + bias[j], f16 MFMA 16x16x32 ----
// (unchanged from R1 -- known-correct; no counter evidence against it yet)
__global__ __launch_bounds__(256) void k_gemm(
    const _Float16* __restrict__ A, const _Float16* __restrict__ B,
    const float* __restrict__ br, const float* __restrict__ bi,
    _Float16* __restrict__ H)
{
    int bid = blockIdx.x;
    int bm = bid >> 2, bn = bid & 3;          // 235 x 4 blocks
    int tid = threadIdx.x;
    int lane = tid & 63, wave = tid >> 6;
    int quad = lane >> 4, l16 = lane & 15;
    int wm = wave >> 1, wn = wave & 1;
    int row0 = bm * 128 + wm * 64;
    int col0 = bn * 128 + wn * 64;

    const _Float16* ap[4];
    const _Float16* bp[4];
#pragma unroll
    for (int mi = 0; mi < 4; mi++) {
        int r = row0 + mi * 16 + l16;
        if (r >= N_NODES) r = N_NODES - 1;    // clamp: garbage rows never stored
        ap[mi] = A + r * NC + quad * 8;
    }
#pragma unroll
    for (int ni = 0; ni < 4; ni++)
        bp[ni] = B + (col0 + ni * 16 + l16) * NC + quad * 8;

    f32x4 acc[4][4] = {};
    for (int k = 0; k < NC; k += 32) {
        f16x8 af[4], bfr[4];
#pragma unroll
        for (int mi = 0; mi < 4; mi++) af[mi] = *reinterpret_cast<const f16x8*>(ap[mi] + k);
#pragma unroll
        for (int ni = 0; ni < 4; ni++) bfr[ni] = *reinterpret_cast<const f16x8*>(bp[ni] + k);
#pragma unroll
        for (int mi = 0; mi < 4; mi++)
#pragma unroll
            for (int ni = 0; ni < 4; ni++)
                acc[mi][ni] = __builtin_amdgcn_mfma_f32_16x16x32_f16(
                    af[mi], bfr[ni], acc[mi][ni], 0, 0, 0);
    }
#pragma unroll
    for (int ni = 0; ni < 4; ni++) {
        int col = col0 + ni * 16 + l16;
        float bias = (col < NC) ? br[col] : bi[col - NC];
        int cc = (col < NC) ? (col * 2) : ((col - NC) * 2 + 1);
#pragma unroll
        for (int mi = 0; mi < 4; mi++) {
            int rowb = row0 + mi * 16 + quad * 4;
#pragma unroll
            for (int r = 0; r < 4; r++) {
                int row = rowb + r;
                if (row < N_NODES) H[row * 512 + cc] = (_Float16)(acc[mi][ni][r] + bias);
            }
        }
    }
}

// ---- evolve: out = x + esc*(h[i] - i*sum_s g_s h[n_s]); accumulate mag stats ----
// NPB=30 -> 1000 blocks (~16 waves/CU vs R1's 4: evolve was 9% occupancy).
#define NPB 30
__global__ __launch_bounds__(256) void k_evolve(
    const float* __restrict__ x, const int* __restrict__ sub_nodes,
    const float* __restrict__ sub_mask, const float* __restrict__ subH,
    const _Float16* __restrict__ h, const float* __restrict__ escp,
    float* __restrict__ outz, _Float16* __restrict__ zbuf, int use_f16,
    float* __restrict__ ssum, float* __restrict__ ssumsq)
{
    __shared__ int   s_nodes[NPB][4];
    __shared__ float s_g[NPB][4];
    __shared__ float s_m0[NPB];
    int tid = threadIdx.x;
    int base = blockIdx.x * NPB;      // 30000 = 1000*30 exactly
    if (tid < NPB) {
        int node = base + tid;
        float fr = 0.f;
#pragma unroll
        for (int t = 0; t < 16; t++) { float v = subH[node * 16 + t]; fr += v * v; }
        // A = -i * H * 1e-4/||H||_F  (eigen- and norm-clamps provably always fire
        // and their scalar factors cancel; Taylor >=2nd order terms are <=5e-9)
        float coef = 1e-4f * rsqrtf(fr);
#pragma unroll
        for (int s = 0; s < 4; s++) {
            s_g[tid][s]     = coef * subH[node * 16 + s] * sub_mask[node * 4 + s];
            s_nodes[tid][s] = sub_nodes[node * 4 + s];
        }
        s_m0[tid] = sub_mask[node * 4];
    }
    __syncthreads();
    float esc = *escp;
    float lsum = 0.f, lsq = 0.f;
    for (int j = 0; j < NPB; j++) {
        int node = base + j;
        float evr = 0.f, evi = 0.f;
#pragma unroll
        for (int s = 0; s < 4; s++) {
            int ns = s_nodes[j][s];
            float g = s_g[j][s];
            f16x2 v = *reinterpret_cast<const f16x2*>(h + ns * 512 + tid * 2);
            float hr = (float)v[0], hi = (float)v[1];
            evr += g * hi;           // -i*g*(hr + i*hi) = g*hi - i*g*hr
            evi -= g * hr;
            if (s == 0) { float m0 = s_m0[j]; evr += m0 * hr; evi += m0 * hi; }
        }
        float xr = x[node * NC + tid];
        float outr = fmaf(esc, evr, xr);
        float outi = esc * evi;
        if (use_f16) {
            f16x2 o; o[0] = (_Float16)outr; o[1] = (_Float16)outi;
            *reinterpret_cast<f16x2*>(zbuf + node * 512 + tid * 2) = o;
        } else {
            outz[node * 512 + tid] = outr;
            outz[node * 512 + 256 + tid] = outi;
        }
        float mag = sqrtf(fmaf(outr, outr, fmaf(outi, outi, 1e-5f)));
        mag = fminf(fmaxf(mag, 1e-5f), 1000.f);
        lsum += mag;
        lsq = fmaf(mag, mag, lsq);
    }
    atomicAdd(&ssum[tid], lsum);     // tid == channel; 1000 adds per address
    atomicAdd(&ssumsq[tid], lsq);
}

// ---- fold batch stats + |lnw|,lnb into per-channel affine: sm = mag*a + b ----
__global__ void k_stats(const float* __restrict__ ssum, const float* __restrict__ ssumsq,
                        const float* __restrict__ lnw, const float* __restrict__ lnb,
                        float* __restrict__ stA, float* __restrict__ stB)
{
    int c = threadIdx.x;
    const float invN = 1.0f / (float)N_NODES;
    float mean = ssum[c] * invN;
    float var = fmaxf(ssumsq[c] * invN - mean * mean, 0.f);
    float denom = sqrtf(var + 1e-5f) + 1e-5f;
    float a = fabsf(lnw[c]) / denom;
    stA[c] = a;
    stB[c] = lnb[c] - mean * a;
}

// ---- layernorm + phase + leaky crelu; 4 channels/thread, 4 nodes/block ----
__global__ __launch_bounds__(256) void k_norm(
    float* __restrict__ out, const _Float16* __restrict__ zbuf, int use_f16,
    const float* __restrict__ stA, const float* __restrict__ stB)
{
    int tid = threadIdx.x;
    int node = blockIdx.x * 4 + (tid >> 6);        // 7500 blocks
    int c0 = (tid & 63) * 4;
    float re[4], im[4];
    if (use_f16) {
        f16x8 z = *reinterpret_cast<const f16x8*>(zbuf + node * 512 + c0 * 2);
#pragma unroll
        for (int e = 0; e < 4; e++) { re[e] = (float)z[2 * e]; im[e] = (float)z[2 * e + 1]; }
    } else {
        float4 r4 = *reinterpret_cast<const float4*>(out + node * 512 + c0);
        float4 i4 = *reinterpret_cast<const float4*>(out + node * 512 + 256 + c0);
        re[0] = r4.x; re[1] = r4.y; re[2] = r4.z; re[3] = r4.w;
        im[0] = i4.x; im[1] = i4.y; im[2] = i4.z; im[3] = i4.w;
    }
    float4 a4 = *reinterpret_cast<const float4*>(stA + c0);
    float4 b4 = *reinterpret_cast<const float4*>(stB + c0);
    float A[4] = {a4.x, a4.y, a4.z, a4.w};
    float B[4] = {b4.x, b4.y, b4.z, b4.w};
    float orr[4], oii[4];
#pragma unroll
    for (int e = 0; e < 4; e++) {
        float r = re[e], i = im[e];
        float mag = sqrtf(fmaf(r, r, fmaf(i, i, 1e-5f)));
        mag = fminf(fmaxf(mag, 1e-5f), 1000.f);
        float sm = fmaf(mag, A[e], B[e]);
        sm = fminf(fmaxf(sm, 1e-5f), 10.0f);
        float px = fminf(fmaxf(r, -1e6f), 1e6f) + 1e-10f;
        float py = fminf(fmaxf(i, -1e6f), 1e6f);
        float r2 = fmaf(px, px, py * py);
        float inv = rsqrtf(r2);
        float zr = sm * px * inv, zi = sm * py * inv;
        zr = fminf(fmaxf(zr, -5.f), 5.f);
        zi = fminf(fmaxf(zi, -5.f), 5.f);
        orr[e] = zr > 0.f ? zr : 0.01f * zr;
        oii[e] = zi > 0.f ? zi : 0.01f * zi;
    }
    *reinterpret_cast<float4*>(out + node * 512 + c0) =
        make_float4(orr[0], orr[1], orr[2], orr[3]);
    *reinterpret_cast<float4*>(out + node * 512 + 256 + c0) =
        make_float4(oii[0], oii[1], oii[2], oii[3]);
}

extern "C" void kernel_launch(void* const* d_in, const int* in_sizes, int n_in,
                              void* d_out, int out_size, void* d_ws, size_t ws_size,
                              hipStream_t stream) {
    const float* x        = (const float*)d_in[0];
    // d_in[1] edge_index: unused (sub_nodes/sub_mask/sub_H are precomputed)
    const int*   sub_nodes = (const int*)d_in[2];
    const float* sub_mask  = (const float*)d_in[3];
    const float* subH      = (const float*)d_in[4];
    const float* wr  = (const float*)d_in[5];
    const float* wi  = (const float*)d_in[6];
    const float* br  = (const float*)d_in[7];
    const float* bi  = (const float*)d_in[8];
    const float* lnw = (const float*)d_in[9];
    const float* lnb = (const float*)d_in[10];
    const float* esc = (const float*)d_in[11];
    float* out = (float*)d_out;

    char* ws = (char*)d_ws;
    const size_t XB_OFF   = 0;                    // 30000*256*2  = 15,360,000
    const size_t WB_OFF   = 15360000;             // 512*256*2    =    262,144
    const size_t H_OFF    = 15622144;             // 30000*512*2  = 30,720,000
    const size_t STAT_OFF = 46342144;             // 4 * 1024
    const size_t ZB_OFF   = 46346240;             // 30000*512*2  = 30,720,000 (optional)
    const size_t WS_NEED_F16 = ZB_OFF + 30720000; // 77,066,240
    _Float16* xb = (_Float16*)(ws + XB_OFF);
    _Float16* Wb = (_Float16*)(ws + WB_OFF);
    _Float16* h  = (_Float16*)(ws + H_OFF);
    float* ssum   = (float*)(ws + STAT_OFF);
    float* ssumsq = (float*)(ws + STAT_OFF + 1024);
    float* stA    = (float*)(ws + STAT_OFF + 2048);
    float* stB    = (float*)(ws + STAT_OFF + 3072);
    _Float16* zbuf = (_Float16*)(ws + ZB_OFF);
    int use_f16 = (ws_size >= WS_NEED_F16) ? 1 : 0;

    hipMemsetAsync(ssum, 0, 2048, stream);
    hipLaunchKernelGGL(k_conv_x, dim3(7500), dim3(256), 0, stream, x, xb);
    hipLaunchKernelGGL(k_conv_w, dim3(128), dim3(256), 0, stream, wr, wi, Wb);
    hipLaunchKernelGGL(k_gemm, dim3(235 * 4), dim3(256), 0, stream, xb, Wb, br, bi, h);
    hipLaunchKernelGGL(k_evolve, dim3(1000), dim3(256), 0, stream,
                       x, sub_nodes, sub_mask, subH, h, esc, out, zbuf, use_f16,
                       ssum, ssumsq);
    hipLaunchKernelGGL(k_stats, dim3(1), dim3(256), 0, stream,
                       ssum, ssumsq, lnw, lnb, stA, stB);
    hipLaunchKernelGGL(k_norm, dim3(7500), dim3(256), 0, stream,
                       out, zbuf, use_f16, stA, stB);
}